// Round 3
// baseline (99.098 us; speedup 1.0000x reference)
//
#include <hip/hip_runtime.h>
#include <hip/hip_bf16.h>
#include <hip/hip_cooperative_groups.h>

namespace cg = cooperative_groups;

// Problem: B=4, L=2048, E=512, D=128
//   dep[b,l,d]  = sum_e emb[b,l,e] * W[d,e]
//   dist[b,i,j] = sq[i] + sq[j] - 2 * dep_b . dep_b
// d_out = dep (8192*128 f32) ++ distances (4*2048*2048 f32)
//
// Round 3: launch-count is the enemy (~5-6us per dispatch in the timed
// graph). ONE cooperative kernel: phase1 (dep + sq) -> grid.sync ->
// phase2 (distance tiles, LDS-staged gram). Fallback to 2 kernels if the
// cooperative launch is rejected.

typedef __attribute__((ext_vector_type(8))) short  short8;   // 8 bf16
typedef __attribute__((ext_vector_type(4))) float  floatx4;  // MFMA C/D frag

#define B_  4
#define L_  2048
#define E_  512
#define D_  128
#define M_  (B_*L_)   // 8192
#define NBLK 512      // 2 blocks/CU on 256 CUs — cooperative co-residency

__device__ __forceinline__ unsigned short f2bfu(float x) {
    __hip_bfloat16 h = __float2bfloat16(x);          // HW RNE on gfx950
    union { __hip_bfloat16 h; unsigned short u; } c; c.h = h; return c.u;
}
__device__ __forceinline__ float bfu2f(unsigned short u) {
    union { unsigned u32; float f; } c; c.u32 = ((unsigned)u) << 16; return c.f;
}
__device__ __forceinline__ short8 cvt8(const float* p) {
    float4 x = *reinterpret_cast<const float4*>(p);
    float4 y = *reinterpret_cast<const float4*>(p + 4);
    short8 t;
    t[0] = (short)f2bfu(x.x); t[1] = (short)f2bfu(x.y);
    t[2] = (short)f2bfu(x.z); t[3] = (short)f2bfu(x.w);
    t[4] = (short)f2bfu(y.x); t[5] = (short)f2bfu(y.y);
    t[6] = (short)f2bfu(y.z); t[7] = (short)f2bfu(y.w);
    return t;
}

// ---------------- phase 1: 16 rows of dep + sq, per block -------------------
__device__ __forceinline__ void phase1(int bid, int tid,
    const float* __restrict__ emb, const float* __restrict__ W,
    float* __restrict__ dep_out, unsigned short* __restrict__ dep_b16,
    float* __restrict__ sq, float* pws /* >=64 floats of LDS */)
{
    const int lane = tid & 63, wave = tid >> 6;      // wave owns cols wave*32..+31
    const int l15 = lane & 15, lg = lane >> 4;
    const long m0 = (long)bid * 16;

    floatx4 acc[2] = { (floatx4){0.f,0.f,0.f,0.f}, (floatx4){0.f,0.f,0.f,0.f} };
    const float* ar = emb + (m0 + l15) * E_;
    const float* b0 = W + (wave * 32 + l15) * E_;
    const float* b1 = W + (wave * 32 + 16 + l15) * E_;

    #pragma unroll
    for (int k0 = 0; k0 < E_; k0 += 32) {
        const int kc = k0 + lg * 8;
        short8 af  = cvt8(ar + kc);
        short8 bf0 = cvt8(b0 + kc);
        short8 bf1 = cvt8(b1 + kc);
        acc[0] = __builtin_amdgcn_mfma_f32_16x16x32_bf16(af, bf0, acc[0], 0, 0, 0);
        acc[1] = __builtin_amdgcn_mfma_f32_16x16x32_bf16(af, bf1, acc[1], 0, 0, 0);
    }

    // C/D layout: col = lane&15, row = (lane>>4)*4 + j  [m89-verified]
    float p[4] = {0.f, 0.f, 0.f, 0.f};
    #pragma unroll
    for (int ni = 0; ni < 2; ++ni) {
        #pragma unroll
        for (int j = 0; j < 4; ++j) {
            float v = acc[ni][j];
            unsigned short us = f2bfu(v);
            long row = m0 + lg * 4 + j;
            int  col = wave * 32 + ni * 16 + l15;
            dep_out[row * D_ + col] = v;
            dep_b16[row * D_ + col] = us;
            float vb = bfu2f(us);
            p[j] += vb * vb;                // sq from bf16-rounded dep (matches gram)
        }
    }
    // reduce each row-partial over the 16-lane (l15) group
    #pragma unroll
    for (int j = 0; j < 4; ++j) {
        #pragma unroll
        for (int off = 1; off < 16; off <<= 1)
            p[j] += __shfl_xor(p[j], off);
    }
    if (l15 == 0) {
        #pragma unroll
        for (int j = 0; j < 4; ++j)
            pws[(lg * 4 + j) * 4 + wave] = p[j];
    }
    __syncthreads();
    if (tid < 16)
        sq[m0 + tid] = pws[tid * 4] + pws[tid * 4 + 1] + pws[tid * 4 + 2] + pws[tid * 4 + 3];
}

// ---------------- phase 2: one 128x128 distance tile ------------------------
__device__ __forceinline__ void phase2(int t, int tid,
    const unsigned short* __restrict__ dep_b16, const float* __restrict__ sq,
    float* __restrict__ dist,
    unsigned short (*Is)[136], unsigned short (*Js)[136])
{
    const int lane = tid & 63, wave = tid >> 6;
    const int wr = wave >> 1, wc = wave & 1;
    const int l15 = lane & 15, lg = lane >> 4;
    const int b  = t >> 8;
    const int i0 = ((t >> 4) & 15) * 128;
    const int j0 = (t & 15) * 128;
    const unsigned short* depb = dep_b16 + (long)b * L_ * D_;

    __syncthreads();        // previous LDS contents fully consumed
    #pragma unroll
    for (int jj = 0; jj < 8; ++jj) {
        int chunk = tid + 256 * jj;               // 0..2047
        int row = chunk >> 4, c8 = chunk & 15;
        *reinterpret_cast<short8*>(&Is[row][c8 * 8]) =
            *reinterpret_cast<const short8*>(depb + (long)(i0 + row) * D_ + c8 * 8);
        *reinterpret_cast<short8*>(&Js[row][c8 * 8]) =
            *reinterpret_cast<const short8*>(depb + (long)(j0 + row) * D_ + c8 * 8);
    }
    __syncthreads();

    floatx4 acc[4][4];
    #pragma unroll
    for (int i = 0; i < 4; ++i)
        #pragma unroll
        for (int j = 0; j < 4; ++j)
            acc[i][j] = (floatx4){0.f, 0.f, 0.f, 0.f};

    #pragma unroll
    for (int kk = 0; kk < 4; ++kk) {
        short8 af[4], bf[4];
        #pragma unroll
        for (int mi = 0; mi < 4; ++mi)
            af[mi] = *reinterpret_cast<const short8*>(&Is[wr * 64 + mi * 16 + l15][kk * 32 + lg * 8]);
        #pragma unroll
        for (int ni = 0; ni < 4; ++ni)
            bf[ni] = *reinterpret_cast<const short8*>(&Js[wc * 64 + ni * 16 + l15][kk * 32 + lg * 8]);
        #pragma unroll
        for (int mi = 0; mi < 4; ++mi)
            #pragma unroll
            for (int ni = 0; ni < 4; ++ni)
                acc[mi][ni] = __builtin_amdgcn_mfma_f32_16x16x32_bf16(
                    af[mi], bf[ni], acc[mi][ni], 0, 0, 0);
    }

    const float* sqb = sq + b * L_;
    float sqc[4];
    #pragma unroll
    for (int ni = 0; ni < 4; ++ni)
        sqc[ni] = sqb[j0 + wc * 64 + ni * 16 + l15];

    float* db = dist + (long)b * L_ * L_;
    #pragma unroll
    for (int mi = 0; mi < 4; ++mi) {
        #pragma unroll
        for (int j = 0; j < 4; ++j) {
            int row = i0 + wr * 64 + mi * 16 + lg * 4 + j;
            float sr = sqb[row];
            #pragma unroll
            for (int ni = 0; ni < 4; ++ni) {
                int col = j0 + wc * 64 + ni * 16 + l15;
                db[(long)row * L_ + col] = sr + sqc[ni] - 2.0f * acc[mi][ni][j];
            }
        }
    }
}

// ---------------- fused cooperative kernel ----------------------------------
__global__ __launch_bounds__(256, 2)
void kFused(const float* __restrict__ emb, const float* __restrict__ W,
            float* __restrict__ dep_out, unsigned short* __restrict__ dep_b16,
            float* __restrict__ sq, float* __restrict__ dist)
{
    __shared__ __align__(16) unsigned short Is[128][136];   // 34816 B
    __shared__ __align__(16) unsigned short Js[128][136];   // 34816 B

    const int bid = blockIdx.x, tid = threadIdx.x;
    phase1(bid, tid, emb, W, dep_out, dep_b16, sq, reinterpret_cast<float*>(&Is[0][0]));

    cg::this_grid().sync();

    phase2(bid,        tid, dep_b16, sq, dist, Is, Js);
    phase2(bid + NBLK, tid, dep_b16, sq, dist, Is, Js);
}

// ---------------- fallback (2 conventional kernels) -------------------------
__global__ __launch_bounds__(256, 2)
void kP1(const float* __restrict__ emb, const float* __restrict__ W,
         float* __restrict__ dep_out, unsigned short* __restrict__ dep_b16,
         float* __restrict__ sq)
{
    __shared__ float pws[64];
    phase1(blockIdx.x, threadIdx.x, emb, W, dep_out, dep_b16, sq, pws);
}

__global__ __launch_bounds__(256, 2)
void kP2(const unsigned short* __restrict__ dep_b16, const float* __restrict__ sq,
         float* __restrict__ dist)
{
    __shared__ __align__(16) unsigned short Is[128][136];
    __shared__ __align__(16) unsigned short Js[128][136];
    phase2(blockIdx.x,        threadIdx.x, dep_b16, sq, dist, Is, Js);
    phase2(blockIdx.x + NBLK, threadIdx.x, dep_b16, sq, dist, Is, Js);
}

extern "C" void kernel_launch(void* const* d_in, const int* in_sizes, int n_in,
                              void* d_out, int out_size, void* d_ws, size_t ws_size,
                              hipStream_t stream)
{
    const float* emb = (const float*)d_in[0];   // [B,L,E] f32
    const float* W   = (const float*)d_in[1];   // [D,E]   f32

    float* dep_out = (float*)d_out;                       // [B*L, D]
    float* dist    = dep_out + (size_t)M_ * D_;           // [B, L, L]

    unsigned short* dep_b16 = (unsigned short*)d_ws;      // 2 MB
    float* sq = (float*)((char*)d_ws + (size_t)M_ * D_ * sizeof(unsigned short)); // 32 KB

    void* args[6] = { (void*)&emb, (void*)&W, (void*)&dep_out,
                      (void*)&dep_b16, (void*)&sq, (void*)&dist };
    hipError_t err = hipLaunchCooperativeKernel((const void*)kFused,
                                                dim3(NBLK), dim3(256),
                                                args, 0, stream);
    if (err != hipSuccess) {
        // capture-safe fallback: 2 conventional launches
        hipLaunchKernelGGL(kP1, dim3(NBLK), dim3(256), 0, stream,
                           emb, W, dep_out, dep_b16, sq);
        hipLaunchKernelGGL(kP2, dim3(NBLK), dim3(256), 0, stream,
                           dep_b16, sq, dist);
    }
}

// Round 4
// 58.810 us; speedup vs baseline: 1.6850x; 1.6850x over previous
//
#include <hip/hip_runtime.h>
#include <hip/hip_bf16.h>

// Problem: B=4, L=2048, E=512, D=128
//   dep[b,l,d]  = sum_e emb[b,l,e] * W[d,e]
//   dist[b,i,j] = sq[i] + sq[j] - 2 * dep_b . dep_b
// d_out = dep (8192*128 f32) ++ distances (4*2048*2048 f32)
//
// Round 4: un-fuse. Two regular kernels, each at its own best occupancy.
//  kP1: dep f32 + dep bf16 + sq, 512 blocks, no real LDS -> VGPR-bound occ.
//  kP2: distances, 1024 blocks, NO LDS / NO barriers, frags direct from
//       L2-resident dep_b16, nontemporal dist stores.

typedef __attribute__((ext_vector_type(8))) short  short8;   // 8 bf16
typedef __attribute__((ext_vector_type(4))) float  floatx4;  // MFMA C/D frag

#define B_  4
#define L_  2048
#define E_  512
#define D_  128
#define M_  (B_*L_)   // 8192

__device__ __forceinline__ unsigned short f2bfu(float x) {
    __hip_bfloat16 h = __float2bfloat16(x);          // HW RNE
    union { __hip_bfloat16 h; unsigned short u; } c; c.h = h; return c.u;
}
__device__ __forceinline__ float bfu2f(unsigned short u) {
    union { unsigned u32; float f; } c; c.u32 = ((unsigned)u) << 16; return c.f;
}
__device__ __forceinline__ short8 cvt8(const float* p) {
    float4 x = *reinterpret_cast<const float4*>(p);
    float4 y = *reinterpret_cast<const float4*>(p + 4);
    short8 t;
    t[0] = (short)f2bfu(x.x); t[1] = (short)f2bfu(x.y);
    t[2] = (short)f2bfu(x.z); t[3] = (short)f2bfu(x.w);
    t[4] = (short)f2bfu(y.x); t[5] = (short)f2bfu(y.y);
    t[6] = (short)f2bfu(y.z); t[7] = (short)f2bfu(y.w);
    return t;
}

// ---------------- kP1: dep (f32+bf16) + sq; 16 rows per block ---------------
__global__ __launch_bounds__(256)
void kP1(const float* __restrict__ emb, const float* __restrict__ W,
         float* __restrict__ dep_out, unsigned short* __restrict__ dep_b16,
         float* __restrict__ sq)
{
    __shared__ float pws[64];
    const int tid  = threadIdx.x;
    const int lane = tid & 63, wave = tid >> 6;      // wave owns cols wave*32..+31
    const int l15 = lane & 15, lg = lane >> 4;
    const long m0 = (long)blockIdx.x * 16;

    floatx4 acc[2] = { (floatx4){0.f,0.f,0.f,0.f}, (floatx4){0.f,0.f,0.f,0.f} };
    const float* ar = emb + (m0 + l15) * E_;
    const float* b0 = W + (wave * 32 + l15) * E_;
    const float* b1 = W + (wave * 32 + 16 + l15) * E_;

    #pragma unroll
    for (int k0 = 0; k0 < E_; k0 += 32) {
        const int kc = k0 + lg * 8;
        short8 af  = cvt8(ar + kc);
        short8 bf0 = cvt8(b0 + kc);
        short8 bf1 = cvt8(b1 + kc);
        acc[0] = __builtin_amdgcn_mfma_f32_16x16x32_bf16(af, bf0, acc[0], 0, 0, 0);
        acc[1] = __builtin_amdgcn_mfma_f32_16x16x32_bf16(af, bf1, acc[1], 0, 0, 0);
    }

    // C/D layout: col = lane&15, row = (lane>>4)*4 + j  [m89-verified]
    float p[4] = {0.f, 0.f, 0.f, 0.f};
    #pragma unroll
    for (int ni = 0; ni < 2; ++ni) {
        #pragma unroll
        for (int j = 0; j < 4; ++j) {
            float v = acc[ni][j];
            unsigned short us = f2bfu(v);
            long row = m0 + lg * 4 + j;
            int  col = wave * 32 + ni * 16 + l15;
            __builtin_nontemporal_store(v, dep_out + row * D_ + col); // write-once
            dep_b16[row * D_ + col] = us;                             // re-read by kP2
            float vb = bfu2f(us);
            p[j] += vb * vb;        // sq from bf16-rounded dep (matches gram numerics)
        }
    }
    #pragma unroll
    for (int j = 0; j < 4; ++j) {
        #pragma unroll
        for (int off = 1; off < 16; off <<= 1)
            p[j] += __shfl_xor(p[j], off);
    }
    if (l15 == 0) {
        #pragma unroll
        for (int j = 0; j < 4; ++j)
            pws[(lg * 4 + j) * 4 + wave] = p[j];
    }
    __syncthreads();
    if (tid < 16)
        sq[m0 + tid] = pws[tid * 4] + pws[tid * 4 + 1] + pws[tid * 4 + 2] + pws[tid * 4 + 3];
}

// ---------------- kP2: dist tile 128x128, LDS-free, barrier-free ------------
__global__ __launch_bounds__(256)
void kP2(const unsigned short* __restrict__ dep_b16, const float* __restrict__ sq,
         float* __restrict__ dist)
{
    const int tid  = threadIdx.x;
    const int lane = tid & 63;
    const int wave = tid >> 6;
    const int wr = wave >> 1, wc = wave & 1;
    const int l15 = lane & 15, lg = lane >> 4;
    const int b  = blockIdx.z;
    const int i0 = blockIdx.y * 128;
    const int j0 = blockIdx.x * 128;
    const unsigned short* depb = dep_b16 + (long)b * L_ * D_;

    floatx4 acc[4][4];
    #pragma unroll
    for (int i = 0; i < 4; ++i)
        #pragma unroll
        for (int j = 0; j < 4; ++j)
            acc[i][j] = (floatx4){0.f, 0.f, 0.f, 0.f};

    const unsigned short* ibase = depb + (long)(i0 + wr * 64 + l15) * D_;
    const unsigned short* jbase = depb + (long)(j0 + wc * 64 + l15) * D_;

    #pragma unroll
    for (int kk = 0; kk < 4; ++kk) {
        const int kc = kk * 32 + lg * 8;
        short8 af[4], bf[4];
        #pragma unroll
        for (int mi = 0; mi < 4; ++mi)
            af[mi] = *reinterpret_cast<const short8*>(ibase + (long)mi * 16 * D_ + kc);
        #pragma unroll
        for (int ni = 0; ni < 4; ++ni)
            bf[ni] = *reinterpret_cast<const short8*>(jbase + (long)ni * 16 * D_ + kc);
        #pragma unroll
        for (int mi = 0; mi < 4; ++mi)
            #pragma unroll
            for (int ni = 0; ni < 4; ++ni)
                acc[mi][ni] = __builtin_amdgcn_mfma_f32_16x16x32_bf16(
                    af[mi], bf[ni], acc[mi][ni], 0, 0, 0);
    }

    const float* sqb = sq + b * L_;
    float sqc[4];
    #pragma unroll
    for (int ni = 0; ni < 4; ++ni)
        sqc[ni] = sqb[j0 + wc * 64 + ni * 16 + l15];

    float* db = dist + (long)b * L_ * L_;
    #pragma unroll
    for (int mi = 0; mi < 4; ++mi) {
        #pragma unroll
        for (int j = 0; j < 4; ++j) {
            int row = i0 + wr * 64 + mi * 16 + lg * 4 + j;
            float sr = sqb[row];
            #pragma unroll
            for (int ni = 0; ni < 4; ++ni) {
                int col = j0 + wc * 64 + ni * 16 + l15;
                __builtin_nontemporal_store(sr + sqc[ni] - 2.0f * acc[mi][ni][j],
                                            db + (long)row * L_ + col);
            }
        }
    }
}

extern "C" void kernel_launch(void* const* d_in, const int* in_sizes, int n_in,
                              void* d_out, int out_size, void* d_ws, size_t ws_size,
                              hipStream_t stream)
{
    const float* emb = (const float*)d_in[0];   // [B,L,E] f32
    const float* W   = (const float*)d_in[1];   // [D,E]   f32

    float* dep_out = (float*)d_out;                       // [B*L, D]
    float* dist    = dep_out + (size_t)M_ * D_;           // [B, L, L]

    unsigned short* dep_b16 = (unsigned short*)d_ws;      // 2 MB
    float* sq = (float*)((char*)d_ws + (size_t)M_ * D_ * sizeof(unsigned short)); // 32 KB

    hipLaunchKernelGGL(kP1, dim3(M_ / 16), dim3(256), 0, stream,
                       emb, W, dep_out, dep_b16, sq);
    hipLaunchKernelGGL(kP2, dim3(L_ / 128, L_ / 128, B_), dim3(256), 0, stream,
                       dep_b16, sq, dist);
}

// Round 5
// 48.059 us; speedup vs baseline: 2.0620x; 1.2237x over previous
//
#include <hip/hip_runtime.h>
#include <hip/hip_bf16.h>

// Problem: B=4, L=2048, E=512, D=128
//   dep[b,l,d]  = sum_e emb[b,l,e] * W[d,e]
//   dist[b,i,j] = sq[i] + sq[j] - 2 * dep_b . dep_b
// d_out = dep (8192*128 f32) ++ distances (4*2048*2048 f32)
//
// Round 5 ledger:
//   R2->R4: nontemporal stores = +7us  -> reverted
//   R1->R2: kB without LDS      = +6us  -> LDS staging reinstated
//   NEW: swapped-operand MFMA (A<->B) transposes C/D layout so each lane
//        holds 4 consecutive cols -> float4/ushort4 stores everywhere.

typedef __attribute__((ext_vector_type(8))) short  short8;   // 8 bf16
typedef __attribute__((ext_vector_type(4))) float  floatx4;  // MFMA C/D frag
typedef __attribute__((ext_vector_type(4))) unsigned short ushortx4;

#define B_  4
#define L_  2048
#define E_  512
#define D_  128
#define M_  (B_*L_)   // 8192

__device__ __forceinline__ unsigned short f2bfu(float x) {
    __hip_bfloat16 h = __float2bfloat16(x);          // HW RNE
    union { __hip_bfloat16 h; unsigned short u; } c; c.h = h; return c.u;
}
__device__ __forceinline__ float bfu2f(unsigned short u) {
    union { unsigned u32; float f; } c; c.u32 = ((unsigned)u) << 16; return c.f;
}
__device__ __forceinline__ short8 cvt8(const float* p) {
    float4 x = *reinterpret_cast<const float4*>(p);
    float4 y = *reinterpret_cast<const float4*>(p + 4);
    short8 t;
    t[0] = (short)f2bfu(x.x); t[1] = (short)f2bfu(x.y);
    t[2] = (short)f2bfu(x.z); t[3] = (short)f2bfu(x.w);
    t[4] = (short)f2bfu(y.x); t[5] = (short)f2bfu(y.y);
    t[6] = (short)f2bfu(y.z); t[7] = (short)f2bfu(y.w);
    return t;
}

// ---------------- kP1: dep (f32+bf16) + sq; 16 rows per block ---------------
// Swapped operands: A = W-frag, B = emb-frag  =>  D row (lg*4+j) = d-index,
// D col (l15) = m-index. Lane holds dep[m0+l15][dbase .. dbase+3] -> float4.
__global__ __launch_bounds__(256)
void kP1(const float* __restrict__ emb, const float* __restrict__ W,
         float* __restrict__ dep_out, unsigned short* __restrict__ dep_b16,
         float* __restrict__ sq)
{
    __shared__ float pws[16][4];
    const int tid  = threadIdx.x;
    const int lane = tid & 63, wave = tid >> 6;      // wave owns d-cols wave*32..+31
    const int l15 = lane & 15, lg = lane >> 4;
    const long m0 = (long)blockIdx.x * 16;

    floatx4 acc[2] = { (floatx4){0.f,0.f,0.f,0.f}, (floatx4){0.f,0.f,0.f,0.f} };
    const float* ar = emb + (m0 + l15) * E_;               // B-operand (emb row)
    const float* w0 = W + (wave * 32 + l15) * E_;          // A-operand ni=0
    const float* w1 = W + (wave * 32 + 16 + l15) * E_;     // A-operand ni=1

    #pragma unroll
    for (int k0 = 0; k0 < E_; k0 += 32) {
        const int kc = k0 + lg * 8;
        short8 bfm = cvt8(ar + kc);
        short8 af0 = cvt8(w0 + kc);
        short8 af1 = cvt8(w1 + kc);
        acc[0] = __builtin_amdgcn_mfma_f32_16x16x32_bf16(af0, bfm, acc[0], 0, 0, 0);
        acc[1] = __builtin_amdgcn_mfma_f32_16x16x32_bf16(af1, bfm, acc[1], 0, 0, 0);
    }

    const long m = m0 + l15;
    float p = 0.f;
    #pragma unroll
    for (int ni = 0; ni < 2; ++ni) {
        const int dbase = wave * 32 + ni * 16 + lg * 4;
        floatx4  v;
        ushortx4 u;
        #pragma unroll
        for (int j = 0; j < 4; ++j) {
            v[j] = acc[ni][j];
            u[j] = f2bfu(v[j]);
            float vb = bfu2f(u[j]);
            p += vb * vb;               // sq from bf16-rounded dep (matches gram)
        }
        *reinterpret_cast<floatx4*>(dep_out + m * D_ + dbase)  = v;
        *reinterpret_cast<ushortx4*>(dep_b16 + m * D_ + dbase) = u;
    }
    // reduce across lg groups (lanes l15, l15+16, +32, +48)
    p += __shfl_xor(p, 16);
    p += __shfl_xor(p, 32);
    if (lane < 16) pws[lane][wave] = p;
    __syncthreads();
    if (tid < 16)
        sq[m0 + tid] = pws[tid][0] + pws[tid][1] + pws[tid][2] + pws[tid][3];
}

// ---------------- kP2: dist tile 128x128, LDS-staged (R1 body) --------------
// Swapped operands: A = J-frag, B = I-frag  =>  D row = j-index, D col = i.
// Lane holds dist[i][jb .. jb+3] -> float4 stores (16 per wave, was 64).
__global__ __launch_bounds__(256)
void kP2(const unsigned short* __restrict__ dep_b16, const float* __restrict__ sq,
         float* __restrict__ dist)
{
    __shared__ __align__(16) unsigned short Is[128][136];   // stride 272B = 17*16B
    __shared__ __align__(16) unsigned short Js[128][136];

    const int tid  = threadIdx.x;
    const int lane = tid & 63;
    const int wave = tid >> 6;
    const int wr = wave >> 1, wc = wave & 1;
    const int l15 = lane & 15, lg = lane >> 4;
    const int b  = blockIdx.z;
    const int i0 = blockIdx.y * 128;
    const int j0 = blockIdx.x * 128;
    const unsigned short* depb = dep_b16 + (long)b * L_ * D_;

    #pragma unroll
    for (int jj = 0; jj < 8; ++jj) {
        int chunk = tid + 256 * jj;               // 0..2047
        int row = chunk >> 4, c8 = chunk & 15;    // 16B chunks, fully coalesced
        *reinterpret_cast<short8*>(&Is[row][c8 * 8]) =
            *reinterpret_cast<const short8*>(depb + (long)(i0 + row) * D_ + c8 * 8);
        *reinterpret_cast<short8*>(&Js[row][c8 * 8]) =
            *reinterpret_cast<const short8*>(depb + (long)(j0 + row) * D_ + c8 * 8);
    }
    __syncthreads();

    floatx4 acc[4][4];
    #pragma unroll
    for (int i = 0; i < 4; ++i)
        #pragma unroll
        for (int j = 0; j < 4; ++j)
            acc[i][j] = (floatx4){0.f, 0.f, 0.f, 0.f};

    #pragma unroll
    for (int kk = 0; kk < 4; ++kk) {
        short8 af[4], bf[4];
        #pragma unroll
        for (int mi = 0; mi < 4; ++mi)
            af[mi] = *reinterpret_cast<const short8*>(&Is[wr * 64 + mi * 16 + l15][kk * 32 + lg * 8]);
        #pragma unroll
        for (int ni = 0; ni < 4; ++ni)
            bf[ni] = *reinterpret_cast<const short8*>(&Js[wc * 64 + ni * 16 + l15][kk * 32 + lg * 8]);
        #pragma unroll
        for (int mi = 0; mi < 4; ++mi)
            #pragma unroll
            for (int ni = 0; ni < 4; ++ni)
                acc[mi][ni] = __builtin_amdgcn_mfma_f32_16x16x32_bf16(
                    bf[ni], af[mi], acc[mi][ni], 0, 0, 0);    // SWAPPED A<->B
    }

    const float* sqb = sq + b * L_;
    float sri[4];
    #pragma unroll
    for (int mi = 0; mi < 4; ++mi)
        sri[mi] = sqb[i0 + wr * 64 + mi * 16 + l15];
    floatx4 sqj[4];
    #pragma unroll
    for (int ni = 0; ni < 4; ++ni)
        sqj[ni] = *reinterpret_cast<const floatx4*>(sqb + j0 + wc * 64 + ni * 16 + lg * 4);

    float* db = dist + (long)b * L_ * L_;
    #pragma unroll
    for (int mi = 0; mi < 4; ++mi) {
        const long i = i0 + wr * 64 + mi * 16 + l15;
        #pragma unroll
        for (int ni = 0; ni < 4; ++ni) {
            const int jb = j0 + wc * 64 + ni * 16 + lg * 4;
            floatx4 v;
            #pragma unroll
            for (int jj = 0; jj < 4; ++jj)
                v[jj] = sri[mi] + sqj[ni][jj] - 2.0f * acc[mi][ni][jj];
            *reinterpret_cast<floatx4*>(db + i * L_ + jb) = v;
        }
    }
}

extern "C" void kernel_launch(void* const* d_in, const int* in_sizes, int n_in,
                              void* d_out, int out_size, void* d_ws, size_t ws_size,
                              hipStream_t stream)
{
    const float* emb = (const float*)d_in[0];   // [B,L,E] f32
    const float* W   = (const float*)d_in[1];   // [D,E]   f32

    float* dep_out = (float*)d_out;                       // [B*L, D]
    float* dist    = dep_out + (size_t)M_ * D_;           // [B, L, L]

    unsigned short* dep_b16 = (unsigned short*)d_ws;      // 2 MB
    float* sq = (float*)((char*)d_ws + (size_t)M_ * D_ * sizeof(unsigned short)); // 32 KB

    hipLaunchKernelGGL(kP1, dim3(M_ / 16), dim3(256), 0, stream,
                       emb, W, dep_out, dep_b16, sq);
    hipLaunchKernelGGL(kP2, dim3(L_ / 128, L_ / 128, B_), dim3(256), 0, stream,
                       dep_b16, sq, dist);
}